// Round 8
// baseline (238.352 us; speedup 1.0000x reference)
//
#include <hip/hip_runtime.h>
#include <hip/hip_fp16.h>
#include <cstdint>
#include <cstddef>

#define T_DIM 5
#define F_DIM 8
#define Z_DIM 16
#define Y_DIM 96
#define X_DIM 96
#define NRAYS 32768
#define K_SAMP 128

// vol   [1][F=8][T=5][Z=16][Y=96][X=96]  strides: f:737280 t:147456 z:9216 y:96 x:1
// fld   f32 [t][z][y][x]  (2.95 MB)
// cellp Cell[t][z][y][x] 16 B = 8 corner halves (11.8 MB)
// wR [tap][ci=(f*16+z_in)][z_out]: 27*128*16
// part[s][t][z][y][x], s = kt*4+fs (SK=12) or fs (SK=4)

struct __align__(16) Cell { __half2 h0, h1, h2, h3; };
// h0=(c000,c001) z0y0(x,x+1); h1=(c010,c011) z0y1; h2=(c100,c101) z1y0; h3=(c110,c111) z1y1

__global__ void prep_w_kernel(const float* __restrict__ w, const float* __restrict__ cb,
                              const float* __restrict__ dw,
                              float* __restrict__ wR, float* __restrict__ bR,
                              unsigned* loU, unsigned* hiU) {
    int i = blockIdx.x * 256 + threadIdx.x;
    if (i < 8) { loU[i] = 0x7F800000u; hiU[i] = 0u; }
    if (i < 27 * 128 * 16) {
        int tap = i >> 11;
        int r   = i & 2047;
        int ci  = r >> 4;
        int z   = r & 15;
        float s = 0.f;
        #pragma unroll
        for (int f = 0; f < 8; ++f)
            s += w[(size_t)((f * 16 + z) * 128 + ci) * 27 + tap] * dw[f];
        wR[i] = s;
    }
    if (i < 16) {
        float s = 0.f;
        #pragma unroll
        for (int f = 0; f < 8; ++f) s += cb[f * 16 + i] * dw[f];
        bR[i] = s;
    }
}

__global__ __launch_bounds__(256) void nearfar_kernel(
        const float* __restrict__ ro, const float* __restrict__ rd,
        float* __restrict__ nearA, float* __restrict__ farA,
        unsigned* loU, unsigned* hiU) {
    int gid = blockIdx.x * 256 + threadIdx.x;          // 0 .. T*NRAYS-1
    int t = gid / NRAYS;                               // block-uniform (128 blocks per t)
    const float* o = ro + (size_t)gid * 3;
    const float* d = rd + (size_t)gid * 3;
    float ox = o[0], oy = o[1], oz = o[2];
    float dx = d[0], dy = d[1], dz = d[2];
    float t1x = (0.f - ox) / dx, t2x = (1.f - ox) / dx;
    float t1y = (0.f - oy) / dy, t2y = (1.f - oy) / dy;
    float t1z = (0.f - oz) / dz, t2z = (1.f - oz) / dz;
    float nr = fmaxf(fmaxf(fminf(t1x, t2x), fminf(t1y, t2y)), fminf(t1z, t2z));
    float fr = fminf(fminf(fmaxf(t1x, t2x), fmaxf(t1y, t2y)), fmaxf(t1z, t2z));
    nr = fmaxf(nr, 0.01f);
    fr = fmaxf(fr, nr + 1e-6f);
    nearA[gid] = nr;
    farA[gid]  = fr;
    float slast = fmaf(0.9921875f, fr - nr, nr);       // starts[:,127]
    float mn = nr, mx = slast;
    #pragma unroll
    for (int off = 32; off > 0; off >>= 1) {
        mn = fminf(mn, __shfl_down(mn, off, 64));
        mx = fmaxf(mx, __shfl_down(mx, off, 64));
    }
    __shared__ float smn[4], smx[4];
    int w = threadIdx.x >> 6;
    if ((threadIdx.x & 63) == 0) { smn[w] = mn; smx[w] = mx; }
    __syncthreads();
    if (threadIdx.x == 0) {
        mn = fminf(fminf(smn[0], smn[1]), fminf(smn[2], smn[3]));
        mx = fmaxf(fmaxf(smx[0], smx[1]), fmaxf(smx[2], smx[3]));
        atomicMin(&loU[t], __float_as_uint(mn));   // positive floats: bit order == value order
        atomicMax(&hiU[t], __float_as_uint(mx));
    }
}

#define FMA16(VV, WPTR) { \
    float4 w0 = *(const float4*)(WPTR); \
    float4 w1 = *(const float4*)((WPTR) + 4); \
    float4 w2 = *(const float4*)((WPTR) + 8); \
    float4 w3 = *(const float4*)((WPTR) + 12); \
    acc[0]  = fmaf(w0.x, VV, acc[0]);  acc[1]  = fmaf(w0.y, VV, acc[1]); \
    acc[2]  = fmaf(w0.z, VV, acc[2]);  acc[3]  = fmaf(w0.w, VV, acc[3]); \
    acc[4]  = fmaf(w1.x, VV, acc[4]);  acc[5]  = fmaf(w1.y, VV, acc[5]); \
    acc[6]  = fmaf(w1.z, VV, acc[6]);  acc[7]  = fmaf(w1.w, VV, acc[7]); \
    acc[8]  = fmaf(w2.x, VV, acc[8]);  acc[9]  = fmaf(w2.y, VV, acc[9]); \
    acc[10] = fmaf(w2.z, VV, acc[10]); acc[11] = fmaf(w2.w, VV, acc[11]); \
    acc[12] = fmaf(w3.x, VV, acc[12]); acc[13] = fmaf(w3.y, VV, acc[13]); \
    acc[14] = fmaf(w3.z, VV, acc[14]); acc[15] = fmaf(w3.w, VV, acc[15]); }

// Stage (ky,kx)=IT loads: 2 feats x 16 z, branchless clamp + select-zero (SAME pad).
#define LOADSTAGE(DST, IT) { \
    const int ky_ = (IT) / 3, kx_ = (IT) % 3; \
    const int yy_ = y + ky_ - 1, xx_ = x + kx_ - 1; \
    const bool v_ = tval && ((unsigned)yy_ < 96u) && ((unsigned)xx_ < 96u); \
    const int off_ = v_ ? (yy_ * 96 + xx_) : 0; \
    const float* p0_ = base0 + off_; \
    const float* p1_ = base1 + off_; \
    _Pragma("unroll") \
    for (int z_ = 0; z_ < 16; ++z_) { \
        float l0_ = p0_[(size_t)z_ * 9216]; \
        float l1_ = p1_[(size_t)z_ * 9216]; \
        DST[0][z_] = v_ ? l0_ : 0.f; \
        DST[1][z_] = v_ ? l1_ : 0.f; \
    } }

#define FMASTAGE(SRC, IT) { \
    const int ky_ = (IT) / 3, kx_ = (IT) % 3; \
    const int tap_ = (kt * 3 + ky_) * 3 + kx_; \
    _Pragma("unroll") \
    for (int fi_ = 0; fi_ < 2; ++fi_) { \
        const float* wp_ = wR + (size_t)(tap_ * 128 + (fs * 2 + fi_) * 16) * 16; \
        _Pragma("unroll") \
        for (int z_ = 0; z_ < 16; ++z_) { \
            FMA16(SRC[fi_][z_], wp_ + z_ * 16); \
        } \
    } }

// Software-pipelined conv reading vol directly (no transpose).
// KTS==1: kt = blockIdx.z>>2 (SK=12). KTS==3: kt loop (SK=4 fallback). block (96,2).
template<int KTS>
__global__ __launch_bounds__(192) void conv_kernel(
        const float* __restrict__ vol, const float* __restrict__ wR,
        float* __restrict__ part) {
    const int x  = threadIdx.x;                  // 0..95
    const int ty = threadIdx.y;                  // 0..1
    const int y  = blockIdx.x * 2 + ty;          // 0..95
    const int t  = blockIdx.y;                   // 0..4
    const int s  = blockIdx.z;                   // SK=12: kt*4+fs ; SK=4: fs
    const int fs = s & 3;
    const int kt_lo = (KTS == 1) ? (s >> 2)     : 0;
    const int kt_hi = (KTS == 1) ? (s >> 2) + 1 : 3;

    float acc[16];
    #pragma unroll
    for (int z = 0; z < 16; ++z) acc[z] = 0.f;

    float* po = part + (size_t)s * 737280;

    if (KTS == 1) {                              // early-out: OOB kt -> zero partial
        int tt0 = t + kt_lo - 1;
        if (tt0 < 0 || tt0 >= T_DIM) {
            #pragma unroll
            for (int z = 0; z < 16; ++z)
                po[(((size_t)t * Z_DIM + z) * Y_DIM + y) * X_DIM + x] = 0.f;
            return;
        }
    }

    for (int kt2 = kt_lo; kt2 < kt_hi; ++kt2) {
        const int kt = kt2;
        const int tt = t + kt - 1;
        const bool tval = (tt >= 0) && (tt < T_DIM);   // block-uniform
        if (!tval) continue;
        const int ttc = tt;
        const float* base0 = vol + (size_t)(fs * 2)     * 737280 + (size_t)ttc * 147456;
        const float* base1 = vol + (size_t)(fs * 2 + 1) * 737280 + (size_t)ttc * 147456;

        float va[2][16], vb[2][16];
        LOADSTAGE(va, 0)
        #pragma unroll
        for (int it = 0; it < 9; ++it) {
            if ((it & 1) == 0) {
                if (it < 8) LOADSTAGE(vb, it + 1)
                FMASTAGE(va, it)
            } else {
                if (it < 8) LOADSTAGE(va, it + 1)
                FMASTAGE(vb, it)
            }
        }
    }

    #pragma unroll
    for (int z = 0; z < 16; ++z)
        po[(((size_t)t * Z_DIM + z) * Y_DIM + y) * X_DIM + x] = acc[z];
}

// fld = sum of SK partials + bias[z]. 184320 float4 groups.
__global__ __launch_bounds__(256) void combine_kernel(
        const float* __restrict__ part, const float* __restrict__ bR,
        float* __restrict__ fld, int SK) {
    int i = blockIdx.x * 256 + threadIdx.x;
    if (i >= 184320) return;
    int z = (i / 2304) & 15;
    float b = bR[z];
    float4 r = make_float4(b, b, b, b);
    const float4* p = (const float4*)part;
    for (int s = 0; s < SK; ++s) {
        float4 a = p[(size_t)s * 184320 + i];
        r.x += a.x; r.y += a.y; r.z += a.z; r.w += a.w;
    }
    ((float4*)fld)[i] = r;
}

// cellp[t][z][y][x] = 8 fp16 corners of cell (z..z+1, y..y+1, x..x+1), clamped at edges.
__global__ __launch_bounds__(256) void pack_kernel(
        const float* __restrict__ fld, Cell* __restrict__ cellp) {
    int i = blockIdx.x * 256 + threadIdx.x;
    if (i >= 737280) return;
    int x = i % 96;
    int r = i / 96;
    int y = r % 96;
    int r2 = r / 96;
    int z = r2 % 16;
    int t = r2 / 16;
    const float* ft = fld + (size_t)t * 147456;
    int xp = min(x + 1, 95);
    int yr0 = y * 96, yr1 = min(y + 1, 95) * 96;
    int zr0 = z * 9216, zr1 = min(z + 1, 15) * 9216;
    float c000 = ft[zr0 + yr0 + x], c001 = ft[zr0 + yr0 + xp];
    float c010 = ft[zr0 + yr1 + x], c011 = ft[zr0 + yr1 + xp];
    float c100 = ft[zr1 + yr0 + x], c101 = ft[zr1 + yr0 + xp];
    float c110 = ft[zr1 + yr1 + x], c111 = ft[zr1 + yr1 + xp];
    Cell cl;
    cl.h0 = __floats2half2_rn(c000, c001);
    cl.h1 = __floats2half2_rn(c010, c011);
    cl.h2 = __floats2half2_rn(c100, c101);
    cl.h3 = __floats2half2_rn(c110, c111);
    cellp[i] = cl;
}

// 4 lanes per ray, 32 samples each (R4-proven). XCD-affinity block remap: b%8 -> XCD,
// so XCD 0..4 serve one t each (2.36 MB, L2-resident); XCD 5..7 share the remainder.
__global__ __launch_bounds__(256) void render_kernel(
        const float* __restrict__ ro, const float* __restrict__ rd,
        const Cell* __restrict__ cellp,
        const float* __restrict__ nearA, const float* __restrict__ farA,
        const unsigned* __restrict__ loU, const unsigned* __restrict__ hiU,
        const float* __restrict__ dens_b, float* __restrict__ out) {
    int b = blockIdx.x;                 // 0..2559
    int b7 = b & 7, bhi = b >> 3;       // bhi 0..319
    int t, seg;
    if (b7 < 5) { t = b7; seg = bhi; }
    else { int j = (b7 - 5) * 320 + bhi; t = j / 192; seg = 320 + j % 192; }
    int c = threadIdx.x & 3;
    int ray = t * NRAYS + seg * 64 + (threadIdx.x >> 2);

    const float* o = ro + (size_t)ray * 3;
    const float* d = rd + (size_t)ray * 3;
    float ox = o[0], oy = o[1], oz = o[2];
    float dx = d[0], dy = d[1], dz = d[2];
    float nr = nearA[ray], fr = farA[ray];
    float span = fr - nr;
    const Cell* vt = cellp + (size_t)t * 147456;
    float db = dens_b[0];

    float step = span * 0.0078125f;
    float s  = fmaf((float)(c * 32), step, nr);
    float mid = s + 0.5f * step;
    float px = fmaf(dx, mid, ox);
    float py = fmaf(dy, mid, oy);
    float pz = fmaf(dz, mid, oz);
    float ddx = dx * step, ddy = dy * step, ddz = dz * step;

    float num = 0.f, den = 0.f, A = 0.f;
    float trans = 1.f;
    int pidx = -1;
    float2 f00 = {0.f, 0.f}, f01 = {0.f, 0.f}, f10 = {0.f, 0.f}, f11 = {0.f, 0.f};
    for (int kk = 0; kk < 32; ++kk) {
        float gx = fminf(fmaxf(px, 0.f), 1.f) * 95.f;
        float gy = fminf(fmaxf(py, 0.f), 1.f) * 95.f;
        float gz = fminf(fmaxf(pz, 0.f), 1.f) * 15.f;
        int x0 = min((int)gx, 94), y0 = min((int)gy, 94), z0 = min((int)gz, 14);
        float fx = gx - (float)x0, fy = gy - (float)y0, fz = gz - (float)z0;

        int idx = z0 * 9216 + y0 * 96 + x0;
        if (idx != pidx) {                    // exec-masked reload; ~1 dwordx4 per new cell
            pidx = idx;
            Cell cl = vt[idx];
            f00 = __half22float2(cl.h0);
            f01 = __half22float2(cl.h1);
            f10 = __half22float2(cl.h2);
            f11 = __half22float2(cl.h3);
        }

        float v00 = f00.x + fx * (f00.y - f00.x);
        float v01 = f01.x + fx * (f01.y - f01.x);
        float v10 = f10.x + fx * (f10.y - f10.x);
        float v11 = f11.x + fx * (f11.y - f11.x);
        float v0  = v00 + fy * (v01 - v00);
        float v1  = v10 + fy * (v11 - v10);
        float pre = v0 + fz * (v1 - v0) + db;

        float u = __expf(-fabsf(pre));
        float dens = fmaxf(pre, 0.f) + __logf(1.f + u);   // softplus
        float dd = dens * step;
        float ex = __expf(-dd);
        float w = (1.f - ex) * trans;
        num = fmaf(w, s, num);
        den += w;
        trans *= ex;
        A += dd;
        s += step; px += ddx; py += ddy; pz += ddz;
    }
    // prefix transmittance across the 4 chunks of this ray
    int lane = threadIdx.x & 63;
    int q = lane & ~3;
    float A0 = __shfl(A, q,     64);
    float A1 = __shfl(A, q + 1, 64);
    float A2 = __shfl(A, q + 2, 64);
    float P = 0.f;
    if (c > 0) P += A0;
    if (c > 1) P += A1;
    if (c > 2) P += A2;
    float sc = __expf(-P);
    float numc = num * sc;
    float denc = den * sc;
    numc += __shfl_xor(numc, 1, 64);
    numc += __shfl_xor(numc, 2, 64);
    denc += __shfl_xor(denc, 1, 64);
    denc += __shfl_xor(denc, 2, 64);
    if (c == 0) {
        float depth = numc / (denc + 1e-10f);
        float lo = __uint_as_float(loU[t]);
        float hi = __uint_as_float(hiU[t]);
        depth = fminf(fmaxf(depth, lo), hi);
        out[ray] = depth;
    }
}

extern "C" void kernel_launch(void* const* d_in, const int* in_sizes, int n_in,
                              void* d_out, int out_size, void* d_ws, size_t ws_size,
                              hipStream_t stream) {
    const float* vol = (const float*)d_in[0];   // [1,8,5,16,96,96]
    const float* ro  = (const float*)d_in[1];   // [5,32768,3]
    const float* rd  = (const float*)d_in[2];   // [5,32768,3]
    const float* cw  = (const float*)d_in[3];   // [128,128,3,3,3]
    const float* cb  = (const float*)d_in[4];   // [128]
    const float* dw  = (const float*)d_in[5];   // [8,1]
    const float* dbp = (const float*)d_in[6];   // [1]
    float* out = (float*)d_out;                 // [5,32768,1] f32

    // Region A (5,898,240 floats, layout kept from prior rounds): fld (737,280) +
    // cellp (2,949,120 f32-equiv). part follows; misc at the end.
    const size_t A_FLOATS = 5898240;
    const size_t misc = 55296 + 32 + 163840 + 163840 + 16 + 64;
    const int SK = (ws_size >= (A_FLOATS + 12ull * 737280 + misc) * 4) ? 12 : 4;

    float* ws      = (float*)d_ws;
    float* fld     = ws;                          // A: [0 .. 737,280)
    Cell*  cellp   = (Cell*)(ws + 737280);        // A: [737,280 .. 3,686,400)
    float* part    = ws + A_FLOATS;               // SK * 737,280
    float* wR      = part + (size_t)SK * 737280;  // 55,296
    float* bR      = wR + 55296;                  // 16 (+pad 32)
    float* nearA   = bR + 32;                     // 163,840
    float* farA    = nearA + 163840;              // 163,840
    unsigned* loU  = (unsigned*)(farA + 163840);  // 8
    unsigned* hiU  = loU + 8;                     // 8

    hipLaunchKernelGGL(prep_w_kernel, dim3(216), dim3(256), 0, stream,
                       cw, cb, dw, wR, bR, loU, hiU);
    hipLaunchKernelGGL(nearfar_kernel, dim3(640), dim3(256), 0, stream,
                       ro, rd, nearA, farA, loU, hiU);
    if (SK == 12) {
        hipLaunchKernelGGL(conv_kernel<1>, dim3(48, 5, 12), dim3(96, 2), 0, stream,
                           vol, wR, part);
    } else {
        hipLaunchKernelGGL(conv_kernel<3>, dim3(48, 5, 4), dim3(96, 2), 0, stream,
                           vol, wR, part);
    }
    hipLaunchKernelGGL(combine_kernel, dim3(720), dim3(256), 0, stream, part, bR, fld, SK);
    hipLaunchKernelGGL(pack_kernel, dim3(2880), dim3(256), 0, stream, fld, cellp);
    hipLaunchKernelGGL(render_kernel, dim3(2560), dim3(256), 0, stream,
                       ro, rd, cellp, nearA, farA, loU, hiU, dbp, out);
}

// Round 9
// 230.100 us; speedup vs baseline: 1.0359x; 1.0359x over previous
//
#include <hip/hip_runtime.h>
#include <hip/hip_fp16.h>
#include <cstdint>
#include <cstddef>

#define T_DIM 5
#define F_DIM 8
#define Z_DIM 16
#define Y_DIM 96
#define X_DIM 96
#define NRAYS 32768
#define K_SAMP 128

// vol   [1][F=8][T=5][Z=16][Y=96][X=96]  strides: f:737280 t:147456 z:9216 y:96 x:1
// volT  [f][t][y][x][z0..15]             (z-contiguous, 23.6 MB) -- dead after conv
// fld   f32 [t][z][y][x]                 (2.95 MB)               -- overlaps dead volT
// cellp Cell[t][z][y][x] 16 B = 8 corner halves                  -- overlaps dead volT
// wR [tap][ci=(f*16+z_in)][z_out]: 27*128*16
// part[s][t][z][y][x], s = kt*4+fs (SK=12) or fs (SK=4)

struct __align__(16) Cell { __half2 h0, h1, h2, h3; };
// h0=(c000,c001) z0y0(x,x+1); h1=(c010,c011) z0y1; h2=(c100,c101) z1y0; h3=(c110,c111) z1y1

// Fused preprocessing: blocks [0,1440) transpose vol -> volT;
// [1440,1656) build reduced weights; [1656,2296) ray near/far + t-extent atomics.
// loU/hiU are pre-initialized via hipMemsetAsync (0xFF / 0x00) on the stream.
__global__ __launch_bounds__(256) void pre_kernel(
        const float* __restrict__ xin, const float* __restrict__ w,
        const float* __restrict__ cb, const float* __restrict__ dw,
        const float* __restrict__ ro, const float* __restrict__ rd,
        float* __restrict__ volT, float* __restrict__ wR, float* __restrict__ bR,
        float* __restrict__ nearA, float* __restrict__ farA,
        unsigned* loU, unsigned* hiU) {
    __shared__ float smn[4], smx[4];
    int blk = blockIdx.x;
    if (blk < 1440) {
        // ---- transpose: volT[(((f*5+t)*96+y)*96+x)*16 + z] = vol[f][t][z][y][x]
        int gid = blk * 256 + threadIdx.x;             // (f,t,y,x)
        if (gid >= 8 * 5 * 96 * 96) return;
        int x = gid % 96;
        int r = gid / 96;
        int y = r % 96;
        int r2 = r / 96;
        int t = r2 % 5;
        int f = r2 / 5;
        const float* src = xin + (size_t)f * 737280 + t * 147456 + y * 96 + x;
        float v[16];
        #pragma unroll
        for (int z = 0; z < 16; ++z) v[z] = src[(size_t)z * 9216];
        float4* dst = (float4*)(volT + (size_t)gid * 16);
        dst[0] = make_float4(v[0], v[1], v[2], v[3]);
        dst[1] = make_float4(v[4], v[5], v[6], v[7]);
        dst[2] = make_float4(v[8], v[9], v[10], v[11]);
        dst[3] = make_float4(v[12], v[13], v[14], v[15]);
    } else if (blk < 1656) {
        // ---- weight reduction: wR[tap][ci][z] = sum_f w[(f*16+z)*128+ci][tap]*dw[f]
        int i = (blk - 1440) * 256 + threadIdx.x;
        if (i < 27 * 128 * 16) {
            int tap = i >> 11;
            int r   = i & 2047;
            int ci  = r >> 4;
            int z   = r & 15;
            float s = 0.f;
            #pragma unroll
            for (int f = 0; f < 8; ++f)
                s += w[(size_t)((f * 16 + z) * 128 + ci) * 27 + tap] * dw[f];
            wR[i] = s;
        }
        if (i < 16) {
            float s = 0.f;
            #pragma unroll
            for (int f = 0; f < 8; ++f) s += cb[f * 16 + i] * dw[f];
            bR[i] = s;
        }
    } else {
        // ---- near/far: 128 blocks per t (t block-uniform)
        int gid = (blk - 1656) * 256 + threadIdx.x;    // 0 .. T*NRAYS-1
        int t = gid >> 15;
        const float* o = ro + (size_t)gid * 3;
        const float* d = rd + (size_t)gid * 3;
        float ox = o[0], oy = o[1], oz = o[2];
        float dx = d[0], dy = d[1], dz = d[2];
        float t1x = (0.f - ox) / dx, t2x = (1.f - ox) / dx;
        float t1y = (0.f - oy) / dy, t2y = (1.f - oy) / dy;
        float t1z = (0.f - oz) / dz, t2z = (1.f - oz) / dz;
        float nr = fmaxf(fmaxf(fminf(t1x, t2x), fminf(t1y, t2y)), fminf(t1z, t2z));
        float fr = fminf(fminf(fmaxf(t1x, t2x), fmaxf(t1y, t2y)), fmaxf(t1z, t2z));
        nr = fmaxf(nr, 0.01f);
        fr = fmaxf(fr, nr + 1e-6f);
        nearA[gid] = nr;
        farA[gid]  = fr;
        float slast = fmaf(0.9921875f, fr - nr, nr);   // starts[:,127]
        float mn = nr, mx = slast;
        #pragma unroll
        for (int off = 32; off > 0; off >>= 1) {
            mn = fminf(mn, __shfl_down(mn, off, 64));
            mx = fmaxf(mx, __shfl_down(mx, off, 64));
        }
        int wv = threadIdx.x >> 6;
        if ((threadIdx.x & 63) == 0) { smn[wv] = mn; smx[wv] = mx; }
        __syncthreads();
        if (threadIdx.x == 0) {
            mn = fminf(fminf(smn[0], smn[1]), fminf(smn[2], smn[3]));
            mx = fmaxf(fmaxf(smx[0], smx[1]), fmaxf(smx[2], smx[3]));
            atomicMin(&loU[t], __float_as_uint(mn));   // positive floats: bit order == value order
            atomicMax(&hiU[t], __float_as_uint(mx));
        }
    }
}

#define FMA16(VV, WPTR) { \
    float4 w0 = *(const float4*)(WPTR); \
    float4 w1 = *(const float4*)((WPTR) + 4); \
    float4 w2 = *(const float4*)((WPTR) + 8); \
    float4 w3 = *(const float4*)((WPTR) + 12); \
    acc[0]  = fmaf(w0.x, VV, acc[0]);  acc[1]  = fmaf(w0.y, VV, acc[1]); \
    acc[2]  = fmaf(w0.z, VV, acc[2]);  acc[3]  = fmaf(w0.w, VV, acc[3]); \
    acc[4]  = fmaf(w1.x, VV, acc[4]);  acc[5]  = fmaf(w1.y, VV, acc[5]); \
    acc[6]  = fmaf(w1.z, VV, acc[6]);  acc[7]  = fmaf(w1.w, VV, acc[7]); \
    acc[8]  = fmaf(w2.x, VV, acc[8]);  acc[9]  = fmaf(w2.y, VV, acc[9]); \
    acc[10] = fmaf(w2.z, VV, acc[10]); acc[11] = fmaf(w2.w, VV, acc[11]); \
    acc[12] = fmaf(w3.x, VV, acc[12]); acc[13] = fmaf(w3.y, VV, acc[13]); \
    acc[14] = fmaf(w3.z, VV, acc[14]); acc[15] = fmaf(w3.w, VV, acc[15]); }

// R4's proven conv. KTS==1: kt fixed from blockIdx.z (SK=12). KTS==3: kt loop (SK=4).
template<int KTS>
__global__ __launch_bounds__(192) void conv_kernel(
        const float* __restrict__ volT, const float* __restrict__ wR,
        float* __restrict__ part) {
    const int x  = threadIdx.x;                  // 0..95
    const int ty = threadIdx.y;                  // 0..1
    const int y  = blockIdx.x * 2 + ty;          // 0..95
    const int t  = blockIdx.y;                   // 0..4
    const int s  = blockIdx.z;                   // SK=12: kt*4+fs ; SK=4: fs
    const int fs = s & 3;
    const int kt_lo = (KTS == 1) ? (s >> 2)     : 0;
    const int kt_hi = (KTS == 1) ? (s >> 2) + 1 : 3;

    float acc[16];
    #pragma unroll
    for (int z = 0; z < 16; ++z) acc[z] = 0.f;

    for (int kt = kt_lo; kt < kt_hi; ++kt) {
        int tt = t + kt - 1;
        if (tt < 0 || tt >= T_DIM) continue;             // block-uniform
        for (int ky = 0; ky < 3; ++ky) {
            int yy = y + ky - 1;
            if (yy < 0 || yy >= Y_DIM) continue;
            for (int kx = 0; kx < 3; ++kx) {
                int xx = x + kx - 1;
                if (xx < 0 || xx >= X_DIM) continue;     // divergent only at lanes 0/95
                const int tap = (kt * 3 + ky) * 3 + kx;
                #pragma unroll
                for (int fi = 0; fi < 2; ++fi) {
                    const int f = fs * 2 + fi;
                    const float4* vp = (const float4*)(volT +
                        ((((size_t)f * T_DIM + tt) * 96 + yy) * 96 + xx) * 16);
                    float4 va = vp[0], vb = vp[1], vc = vp[2], vd = vp[3];
                    const float* wp = wR + (size_t)(tap * 128 + f * 16) * 16;
                    FMA16(va.x, wp);        FMA16(va.y, wp + 16);
                    FMA16(va.z, wp + 32);   FMA16(va.w, wp + 48);
                    FMA16(vb.x, wp + 64);   FMA16(vb.y, wp + 80);
                    FMA16(vb.z, wp + 96);   FMA16(vb.w, wp + 112);
                    FMA16(vc.x, wp + 128);  FMA16(vc.y, wp + 144);
                    FMA16(vc.z, wp + 160);  FMA16(vc.w, wp + 176);
                    FMA16(vd.x, wp + 192);  FMA16(vd.y, wp + 208);
                    FMA16(vd.z, wp + 224);  FMA16(vd.w, wp + 240);
                }
            }
        }
    }
    float* po = part + (size_t)s * 737280;
    #pragma unroll
    for (int z = 0; z < 16; ++z)
        po[(((size_t)t * Z_DIM + z) * Y_DIM + y) * X_DIM + x] = acc[z];
}

// fld = sum of SK partials + bias[z]. 184320 float4 groups.
__global__ __launch_bounds__(256) void combine_kernel(
        const float* __restrict__ part, const float* __restrict__ bR,
        float* __restrict__ fld, int SK) {
    int i = blockIdx.x * 256 + threadIdx.x;
    if (i >= 184320) return;
    int z = (i / 2304) & 15;
    float b = bR[z];
    float4 r = make_float4(b, b, b, b);
    const float4* p = (const float4*)part;
    for (int s = 0; s < SK; ++s) {
        float4 a = p[(size_t)s * 184320 + i];
        r.x += a.x; r.y += a.y; r.z += a.z; r.w += a.w;
    }
    ((float4*)fld)[i] = r;
}

// Vectorized pack: one thread builds 4 consecutive cells from 4 float4 row loads
// + 4 edge scalars; 64 B contiguous Cell writes.
__global__ __launch_bounds__(256) void pack_kernel(
        const float* __restrict__ fld, Cell* __restrict__ cellp) {
    int j = blockIdx.x * 256 + threadIdx.x;        // 0 .. 184319
    if (j >= 184320) return;
    int x0 = (j % 24) * 4;                         // 0,4,...,92
    int r  = j / 24;
    int y  = r % 96;
    int r2 = r / 96;
    int z  = r2 % 16;
    int t  = r2 / 16;
    const float* ft = fld + (size_t)t * 147456;
    int y1 = min(y + 1, 95), z1 = min(z + 1, 15);
    const float* r00 = ft + z * 9216 + y * 96;     // z0 y0
    const float* r01 = ft + z * 9216 + y1 * 96;    // z0 y1
    const float* r10 = ft + z1 * 9216 + y * 96;    // z1 y0
    const float* r11 = ft + z1 * 9216 + y1 * 96;   // z1 y1
    bool in5 = (x0 + 4) <= 95;
    float4 q00 = *(const float4*)(r00 + x0);
    float4 q01 = *(const float4*)(r01 + x0);
    float4 q10 = *(const float4*)(r10 + x0);
    float4 q11 = *(const float4*)(r11 + x0);
    float v00[5] = {q00.x, q00.y, q00.z, q00.w, in5 ? r00[x0 + 4] : q00.w};
    float v01[5] = {q01.x, q01.y, q01.z, q01.w, in5 ? r01[x0 + 4] : q01.w};
    float v10[5] = {q10.x, q10.y, q10.z, q10.w, in5 ? r10[x0 + 4] : q10.w};
    float v11[5] = {q11.x, q11.y, q11.z, q11.w, in5 ? r11[x0 + 4] : q11.w};
    Cell* cp = cellp + (((size_t)t * 16 + z) * 96 + y) * 96 + x0;
    #pragma unroll
    for (int k = 0; k < 4; ++k) {
        Cell cl;
        cl.h0 = __floats2half2_rn(v00[k], v00[k + 1]);
        cl.h1 = __floats2half2_rn(v01[k], v01[k + 1]);
        cl.h2 = __floats2half2_rn(v10[k], v10[k + 1]);
        cl.h3 = __floats2half2_rn(v11[k], v11[k + 1]);
        cp[k] = cl;
    }
}

// 4 lanes per ray, 32 samples each (R4-proven). XCD-affinity block remap: b%8 -> XCD,
// so XCD 0..4 serve one t each (2.36 MB, L2-resident); XCD 5..7 share the remainder.
__global__ __launch_bounds__(256) void render_kernel(
        const float* __restrict__ ro, const float* __restrict__ rd,
        const Cell* __restrict__ cellp,
        const float* __restrict__ nearA, const float* __restrict__ farA,
        const unsigned* __restrict__ loU, const unsigned* __restrict__ hiU,
        const float* __restrict__ dens_b, float* __restrict__ out) {
    int b = blockIdx.x;                 // 0..2559
    int b7 = b & 7, bhi = b >> 3;       // bhi 0..319
    int t, seg;
    if (b7 < 5) { t = b7; seg = bhi; }
    else { int j = (b7 - 5) * 320 + bhi; t = j / 192; seg = 320 + j % 192; }
    int c = threadIdx.x & 3;
    int ray = t * NRAYS + seg * 64 + (threadIdx.x >> 2);

    const float* o = ro + (size_t)ray * 3;
    const float* d = rd + (size_t)ray * 3;
    float ox = o[0], oy = o[1], oz = o[2];
    float dx = d[0], dy = d[1], dz = d[2];
    float nr = nearA[ray], fr = farA[ray];
    float span = fr - nr;
    const Cell* vt = cellp + (size_t)t * 147456;
    float db = dens_b[0];

    float step = span * 0.0078125f;
    float s  = fmaf((float)(c * 32), step, nr);
    float mid = s + 0.5f * step;
    float px = fmaf(dx, mid, ox);
    float py = fmaf(dy, mid, oy);
    float pz = fmaf(dz, mid, oz);
    float ddx = dx * step, ddy = dy * step, ddz = dz * step;

    float num = 0.f, den = 0.f, A = 0.f;
    float trans = 1.f;
    int pidx = -1;
    float2 f00 = {0.f, 0.f}, f01 = {0.f, 0.f}, f10 = {0.f, 0.f}, f11 = {0.f, 0.f};
    for (int kk = 0; kk < 32; ++kk) {
        float gx = fminf(fmaxf(px, 0.f), 1.f) * 95.f;
        float gy = fminf(fmaxf(py, 0.f), 1.f) * 95.f;
        float gz = fminf(fmaxf(pz, 0.f), 1.f) * 15.f;
        int x0 = min((int)gx, 94), y0 = min((int)gy, 94), z0 = min((int)gz, 14);
        float fx = gx - (float)x0, fy = gy - (float)y0, fz = gz - (float)z0;

        int idx = z0 * 9216 + y0 * 96 + x0;
        if (idx != pidx) {                    // exec-masked reload; ~1 dwordx4 per new cell
            pidx = idx;
            Cell cl = vt[idx];
            f00 = __half22float2(cl.h0);
            f01 = __half22float2(cl.h1);
            f10 = __half22float2(cl.h2);
            f11 = __half22float2(cl.h3);
        }

        float v00 = f00.x + fx * (f00.y - f00.x);
        float v01 = f01.x + fx * (f01.y - f01.x);
        float v10 = f10.x + fx * (f10.y - f10.x);
        float v11 = f11.x + fx * (f11.y - f11.x);
        float v0  = v00 + fy * (v01 - v00);
        float v1  = v10 + fy * (v11 - v10);
        float pre = v0 + fz * (v1 - v0) + db;

        float u = __expf(-fabsf(pre));
        float dens = fmaxf(pre, 0.f) + __logf(1.f + u);   // softplus
        float dd = dens * step;
        float ex = __expf(-dd);
        float w = (1.f - ex) * trans;
        num = fmaf(w, s, num);
        den += w;
        trans *= ex;
        A += dd;
        s += step; px += ddx; py += ddy; pz += ddz;
    }
    // prefix transmittance across the 4 chunks of this ray
    int lane = threadIdx.x & 63;
    int q = lane & ~3;
    float A0 = __shfl(A, q,     64);
    float A1 = __shfl(A, q + 1, 64);
    float A2 = __shfl(A, q + 2, 64);
    float P = 0.f;
    if (c > 0) P += A0;
    if (c > 1) P += A1;
    if (c > 2) P += A2;
    float sc = __expf(-P);
    float numc = num * sc;
    float denc = den * sc;
    numc += __shfl_xor(numc, 1, 64);
    numc += __shfl_xor(numc, 2, 64);
    denc += __shfl_xor(denc, 1, 64);
    denc += __shfl_xor(denc, 2, 64);
    if (c == 0) {
        float depth = numc / (denc + 1e-10f);
        float lo = __uint_as_float(loU[t]);
        float hi = __uint_as_float(hiU[t]);
        depth = fminf(fmaxf(depth, lo), hi);
        out[ray] = depth;
    }
}

extern "C" void kernel_launch(void* const* d_in, const int* in_sizes, int n_in,
                              void* d_out, int out_size, void* d_ws, size_t ws_size,
                              hipStream_t stream) {
    const float* vol = (const float*)d_in[0];   // [1,8,5,16,96,96]
    const float* ro  = (const float*)d_in[1];   // [5,32768,3]
    const float* rd  = (const float*)d_in[2];   // [5,32768,3]
    const float* cw  = (const float*)d_in[3];   // [128,128,3,3,3]
    const float* cb  = (const float*)d_in[4];   // [128]
    const float* dw  = (const float*)d_in[5];   // [8,1]
    const float* dbp = (const float*)d_in[6];   // [1]
    float* out = (float*)d_out;                 // [5,32768,1] f32

    // Region A (5,898,240 floats): volT during conv; fld (737,280) + cellp (2,949,120)
    // after conv (volT dead). part follows; misc at the end.
    const size_t A_FLOATS = 5898240;
    const size_t misc = 55296 + 32 + 163840 + 163840 + 16 + 64;
    const int SK = (ws_size >= (A_FLOATS + 12ull * 737280 + misc) * 4) ? 12 : 4;

    float* ws      = (float*)d_ws;
    float* volT    = ws;                          // A: [0 .. 5,898,240)
    float* fld     = ws;                          // A: [0 .. 737,280)  (after conv)
    Cell*  cellp   = (Cell*)(ws + 737280);        // A: [737,280 .. 3,686,400)
    float* part    = ws + A_FLOATS;               // SK * 737,280
    float* wR      = part + (size_t)SK * 737280;  // 55,296
    float* bR      = wR + 55296;                  // 16 (+pad 32)
    float* nearA   = bR + 32;                     // 163,840
    float* farA    = nearA + 163840;              // 163,840
    unsigned* loU  = (unsigned*)(farA + 163840);  // 8
    unsigned* hiU  = loU + 8;                     // 8

    // loU = 0xFFFFFFFF (uint-max, safe for atomicMin on positive-float bits);
    // hiU = 0 (safe for atomicMax).
    hipMemsetAsync(loU, 0xFF, 8 * sizeof(unsigned), stream);
    hipMemsetAsync(hiU, 0x00, 8 * sizeof(unsigned), stream);

    hipLaunchKernelGGL(pre_kernel, dim3(2296), dim3(256), 0, stream,
                       vol, cw, cb, dw, ro, rd, volT, wR, bR, nearA, farA, loU, hiU);
    if (SK == 12) {
        hipLaunchKernelGGL(conv_kernel<1>, dim3(48, 5, 12), dim3(96, 2), 0, stream,
                           volT, wR, part);
    } else {
        hipLaunchKernelGGL(conv_kernel<3>, dim3(48, 5, 4), dim3(96, 2), 0, stream,
                           volT, wR, part);
    }
    hipLaunchKernelGGL(combine_kernel, dim3(720), dim3(256), 0, stream, part, bR, fld, SK);
    hipLaunchKernelGGL(pack_kernel, dim3(720), dim3(256), 0, stream, fld, cellp);
    hipLaunchKernelGGL(render_kernel, dim3(2560), dim3(256), 0, stream,
                       ro, rd, cellp, nearA, farA, loU, hiU, dbp, out);
}

// Round 10
// 229.994 us; speedup vs baseline: 1.0363x; 1.0005x over previous
//
#include <hip/hip_runtime.h>
#include <hip/hip_fp16.h>
#include <cstdint>
#include <cstddef>

#define T_DIM 5
#define F_DIM 8
#define Z_DIM 16
#define Y_DIM 96
#define X_DIM 96
#define NRAYS 32768
#define K_SAMP 128

// vol   [1][F=8][T=5][Z=16][Y=96][X=96]  strides: f:737280 t:147456 z:9216 y:96 x:1
// fld   f32 [t][z][y][x]  (2.95 MB), conv accumulates via atomicAdd (no bias)
// cellp Cell[t][z][y][x] 16 B = 8 corner halves (bias folded in at pack)
// wR [tap][ci=(f*16+z_in)][z_out]: 27*128*16

struct __align__(16) Cell { __half2 h0, h1, h2, h3; };
// h0=(c000,c001) z0y0(x,x+1); h1=(c010,c011) z0y1; h2=(c100,c101) z1y0; h3=(c110,c111) z1y1

// Fused preprocessing: blocks [0,216) reduced weights; [216,856) ray near/far.
// loU/hiU pre-initialized via hipMemsetAsync (0xFF / 0x00).
__global__ __launch_bounds__(256) void pre_kernel(
        const float* __restrict__ w, const float* __restrict__ cb,
        const float* __restrict__ dw,
        const float* __restrict__ ro, const float* __restrict__ rd,
        float* __restrict__ wR, float* __restrict__ bR,
        float* __restrict__ nearA, float* __restrict__ farA,
        unsigned* loU, unsigned* hiU) {
    __shared__ float smn[4], smx[4];
    int blk = blockIdx.x;
    if (blk < 216) {
        // wR[tap][ci][z] = sum_f w[(f*16+z)*128+ci][tap] * dw[f]
        int i = blk * 256 + threadIdx.x;
        if (i < 27 * 128 * 16) {
            int tap = i >> 11;
            int r   = i & 2047;
            int ci  = r >> 4;
            int z   = r & 15;
            float s = 0.f;
            #pragma unroll
            for (int f = 0; f < 8; ++f)
                s += w[(size_t)((f * 16 + z) * 128 + ci) * 27 + tap] * dw[f];
            wR[i] = s;
        }
        if (i < 16) {
            float s = 0.f;
            #pragma unroll
            for (int f = 0; f < 8; ++f) s += cb[f * 16 + i] * dw[f];
            bR[i] = s;
        }
    } else {
        // near/far: 128 blocks per t (t block-uniform)
        int gid = (blk - 216) * 256 + threadIdx.x;     // 0 .. T*NRAYS-1
        int t = gid >> 15;
        const float* o = ro + (size_t)gid * 3;
        const float* d = rd + (size_t)gid * 3;
        float ox = o[0], oy = o[1], oz = o[2];
        float dx = d[0], dy = d[1], dz = d[2];
        float t1x = (0.f - ox) / dx, t2x = (1.f - ox) / dx;
        float t1y = (0.f - oy) / dy, t2y = (1.f - oy) / dy;
        float t1z = (0.f - oz) / dz, t2z = (1.f - oz) / dz;
        float nr = fmaxf(fmaxf(fminf(t1x, t2x), fminf(t1y, t2y)), fminf(t1z, t2z));
        float fr = fminf(fminf(fmaxf(t1x, t2x), fmaxf(t1y, t2y)), fmaxf(t1z, t2z));
        nr = fmaxf(nr, 0.01f);
        fr = fmaxf(fr, nr + 1e-6f);
        nearA[gid] = nr;
        farA[gid]  = fr;
        float slast = fmaf(0.9921875f, fr - nr, nr);   // starts[:,127]
        float mn = nr, mx = slast;
        #pragma unroll
        for (int off = 32; off > 0; off >>= 1) {
            mn = fminf(mn, __shfl_down(mn, off, 64));
            mx = fmaxf(mx, __shfl_down(mx, off, 64));
        }
        int wv = threadIdx.x >> 6;
        if ((threadIdx.x & 63) == 0) { smn[wv] = mn; smx[wv] = mx; }
        __syncthreads();
        if (threadIdx.x == 0) {
            mn = fminf(fminf(smn[0], smn[1]), fminf(smn[2], smn[3]));
            mx = fmaxf(fmaxf(smx[0], smx[1]), fmaxf(smx[2], smx[3]));
            atomicMin(&loU[t], __float_as_uint(mn));   // positive floats: bit order == value order
            atomicMax(&hiU[t], __float_as_uint(mx));
        }
    }
}

#define FMA16(VV, WPTR) { \
    float4 w0 = *(const float4*)(WPTR); \
    float4 w1 = *(const float4*)((WPTR) + 4); \
    float4 w2 = *(const float4*)((WPTR) + 8); \
    float4 w3 = *(const float4*)((WPTR) + 12); \
    acc[0]  = fmaf(w0.x, VV, acc[0]);  acc[1]  = fmaf(w0.y, VV, acc[1]); \
    acc[2]  = fmaf(w0.z, VV, acc[2]);  acc[3]  = fmaf(w0.w, VV, acc[3]); \
    acc[4]  = fmaf(w1.x, VV, acc[4]);  acc[5]  = fmaf(w1.y, VV, acc[5]); \
    acc[6]  = fmaf(w1.z, VV, acc[6]);  acc[7]  = fmaf(w1.w, VV, acc[7]); \
    acc[8]  = fmaf(w2.x, VV, acc[8]);  acc[9]  = fmaf(w2.y, VV, acc[9]); \
    acc[10] = fmaf(w2.z, VV, acc[10]); acc[11] = fmaf(w2.w, VV, acc[11]); \
    acc[12] = fmaf(w3.x, VV, acc[12]); acc[13] = fmaf(w3.y, VV, acc[13]); \
    acc[14] = fmaf(w3.z, VV, acc[14]); acc[15] = fmaf(w3.w, VV, acc[15]); }

// R3-proven conv inner loop (direct vol reads, 16-z batched gather), SK=12 grid,
// atomicAdd epilogue into fld (fld pre-zeroed; bias added in pack).
__global__ __launch_bounds__(192) void conv_kernel(
        const float* __restrict__ xin, const float* __restrict__ wR,
        float* __restrict__ fld) {
    const int x  = threadIdx.x;                  // 0..95
    const int ty = threadIdx.y;                  // 0..1
    const int y  = blockIdx.x * 2 + ty;          // 0..95
    const int t  = blockIdx.y;                   // 0..4
    const int s  = blockIdx.z;                   // kt*4 + fs
    const int fs = s & 3;
    const int kt = s >> 2;

    const int tt = t + kt - 1;
    if (tt < 0 || tt >= T_DIM) return;           // OOB kt contributes nothing

    float acc[16];
    #pragma unroll
    for (int z = 0; z < 16; ++z) acc[z] = 0.f;

    for (int ky = 0; ky < 3; ++ky) {
        int yy = y + ky - 1;
        if (yy < 0 || yy >= Y_DIM) continue;
        for (int kx = 0; kx < 3; ++kx) {
            int xx = x + kx - 1;
            if (xx < 0 || xx >= X_DIM) continue;     // divergent only at lanes 0/95
            const int tap = (kt * 3 + ky) * 3 + kx;
            #pragma unroll
            for (int fi = 0; fi < 2; ++fi) {
                const int f = fs * 2 + fi;
                const float* xp = xin + (size_t)f * 737280 + tt * 147456 + yy * 96 + xx;
                float v[16];                         // batch 16 gathers -> deep MLP
                #pragma unroll
                for (int zi = 0; zi < 16; ++zi) v[zi] = xp[(size_t)zi * 9216];
                const float* wp = wR + (size_t)(tap * 128 + f * 16) * 16;
                #pragma unroll
                for (int zi = 0; zi < 16; ++zi) {
                    FMA16(v[zi], wp + zi * 16);
                }
            }
        }
    }
    #pragma unroll
    for (int z = 0; z < 16; ++z)
        atomicAdd(&fld[(((size_t)t * Z_DIM + z) * Y_DIM + y) * X_DIM + x], acc[z]);
}

// Vectorized pack: one thread builds 4 consecutive cells from 4 float4 row loads
// + 4 edge scalars; adds per-z bias; 64 B contiguous Cell writes.
__global__ __launch_bounds__(256) void pack_kernel(
        const float* __restrict__ fld, const float* __restrict__ bR,
        Cell* __restrict__ cellp) {
    int j = blockIdx.x * 256 + threadIdx.x;        // 0 .. 184319
    if (j >= 184320) return;
    int x0 = (j % 24) * 4;                         // 0,4,...,92
    int r  = j / 24;
    int y  = r % 96;
    int r2 = r / 96;
    int z  = r2 % 16;
    int t  = r2 / 16;
    const float* ft = fld + (size_t)t * 147456;
    int y1 = min(y + 1, 95), z1 = min(z + 1, 15);
    float bz0 = bR[z], bz1 = bR[z1];
    const float* r00 = ft + z * 9216 + y * 96;     // z0 y0
    const float* r01 = ft + z * 9216 + y1 * 96;    // z0 y1
    const float* r10 = ft + z1 * 9216 + y * 96;    // z1 y0
    const float* r11 = ft + z1 * 9216 + y1 * 96;   // z1 y1
    bool in5 = (x0 + 4) <= 95;
    float4 q00 = *(const float4*)(r00 + x0);
    float4 q01 = *(const float4*)(r01 + x0);
    float4 q10 = *(const float4*)(r10 + x0);
    float4 q11 = *(const float4*)(r11 + x0);
    float v00[5] = {q00.x + bz0, q00.y + bz0, q00.z + bz0, q00.w + bz0,
                    (in5 ? r00[x0 + 4] : q00.w) + bz0};
    float v01[5] = {q01.x + bz0, q01.y + bz0, q01.z + bz0, q01.w + bz0,
                    (in5 ? r01[x0 + 4] : q01.w) + bz0};
    float v10[5] = {q10.x + bz1, q10.y + bz1, q10.z + bz1, q10.w + bz1,
                    (in5 ? r10[x0 + 4] : q10.w) + bz1};
    float v11[5] = {q11.x + bz1, q11.y + bz1, q11.z + bz1, q11.w + bz1,
                    (in5 ? r11[x0 + 4] : q11.w) + bz1};
    Cell* cp = cellp + (((size_t)t * 16 + z) * 96 + y) * 96 + x0;
    #pragma unroll
    for (int k = 0; k < 4; ++k) {
        Cell cl;
        cl.h0 = __floats2half2_rn(v00[k], v00[k + 1]);
        cl.h1 = __floats2half2_rn(v01[k], v01[k + 1]);
        cl.h2 = __floats2half2_rn(v10[k], v10[k + 1]);
        cl.h3 = __floats2half2_rn(v11[k], v11[k + 1]);
        cp[k] = cl;
    }
}

// 4 lanes per ray, 32 samples each (R4-proven). XCD-affinity block remap: b%8 -> XCD,
// so XCD 0..4 serve one t each (2.36 MB, L2-resident); XCD 5..7 share the remainder.
__global__ __launch_bounds__(256) void render_kernel(
        const float* __restrict__ ro, const float* __restrict__ rd,
        const Cell* __restrict__ cellp,
        const float* __restrict__ nearA, const float* __restrict__ farA,
        const unsigned* __restrict__ loU, const unsigned* __restrict__ hiU,
        const float* __restrict__ dens_b, float* __restrict__ out) {
    int b = blockIdx.x;                 // 0..2559
    int b7 = b & 7, bhi = b >> 3;       // bhi 0..319
    int t, seg;
    if (b7 < 5) { t = b7; seg = bhi; }
    else { int j = (b7 - 5) * 320 + bhi; t = j / 192; seg = 320 + j % 192; }
    int c = threadIdx.x & 3;
    int ray = t * NRAYS + seg * 64 + (threadIdx.x >> 2);

    const float* o = ro + (size_t)ray * 3;
    const float* d = rd + (size_t)ray * 3;
    float ox = o[0], oy = o[1], oz = o[2];
    float dx = d[0], dy = d[1], dz = d[2];
    float nr = nearA[ray], fr = farA[ray];
    float span = fr - nr;
    const Cell* vt = cellp + (size_t)t * 147456;
    float db = dens_b[0];

    float step = span * 0.0078125f;
    float s  = fmaf((float)(c * 32), step, nr);
    float mid = s + 0.5f * step;
    float px = fmaf(dx, mid, ox);
    float py = fmaf(dy, mid, oy);
    float pz = fmaf(dz, mid, oz);
    float ddx = dx * step, ddy = dy * step, ddz = dz * step;

    float num = 0.f, den = 0.f, A = 0.f;
    float trans = 1.f;
    int pidx = -1;
    float2 f00 = {0.f, 0.f}, f01 = {0.f, 0.f}, f10 = {0.f, 0.f}, f11 = {0.f, 0.f};
    for (int kk = 0; kk < 32; ++kk) {
        float gx = fminf(fmaxf(px, 0.f), 1.f) * 95.f;
        float gy = fminf(fmaxf(py, 0.f), 1.f) * 95.f;
        float gz = fminf(fmaxf(pz, 0.f), 1.f) * 15.f;
        int x0 = min((int)gx, 94), y0 = min((int)gy, 94), z0 = min((int)gz, 14);
        float fx = gx - (float)x0, fy = gy - (float)y0, fz = gz - (float)z0;

        int idx = z0 * 9216 + y0 * 96 + x0;
        if (idx != pidx) {                    // exec-masked reload; ~1 dwordx4 per new cell
            pidx = idx;
            Cell cl = vt[idx];
            f00 = __half22float2(cl.h0);
            f01 = __half22float2(cl.h1);
            f10 = __half22float2(cl.h2);
            f11 = __half22float2(cl.h3);
        }

        float v00 = f00.x + fx * (f00.y - f00.x);
        float v01 = f01.x + fx * (f01.y - f01.x);
        float v10 = f10.x + fx * (f10.y - f10.x);
        float v11 = f11.x + fx * (f11.y - f11.x);
        float v0  = v00 + fy * (v01 - v00);
        float v1  = v10 + fy * (v11 - v10);
        float pre = v0 + fz * (v1 - v0) + db;

        float u = __expf(-fabsf(pre));
        float dens = fmaxf(pre, 0.f) + __logf(1.f + u);   // softplus
        float dd = dens * step;
        float ex = __expf(-dd);
        float w = (1.f - ex) * trans;
        num = fmaf(w, s, num);
        den += w;
        trans *= ex;
        A += dd;
        s += step; px += ddx; py += ddy; pz += ddz;
    }
    // prefix transmittance across the 4 chunks of this ray
    int lane = threadIdx.x & 63;
    int q = lane & ~3;
    float A0 = __shfl(A, q,     64);
    float A1 = __shfl(A, q + 1, 64);
    float A2 = __shfl(A, q + 2, 64);
    float P = 0.f;
    if (c > 0) P += A0;
    if (c > 1) P += A1;
    if (c > 2) P += A2;
    float sc = __expf(-P);
    float numc = num * sc;
    float denc = den * sc;
    numc += __shfl_xor(numc, 1, 64);
    numc += __shfl_xor(numc, 2, 64);
    denc += __shfl_xor(denc, 1, 64);
    denc += __shfl_xor(denc, 2, 64);
    if (c == 0) {
        float depth = numc / (denc + 1e-10f);
        float lo = __uint_as_float(loU[t]);
        float hi = __uint_as_float(hiU[t]);
        depth = fminf(fmaxf(depth, lo), hi);
        out[ray] = depth;
    }
}

extern "C" void kernel_launch(void* const* d_in, const int* in_sizes, int n_in,
                              void* d_out, int out_size, void* d_ws, size_t ws_size,
                              hipStream_t stream) {
    const float* vol = (const float*)d_in[0];   // [1,8,5,16,96,96]
    const float* ro  = (const float*)d_in[1];   // [5,32768,3]
    const float* rd  = (const float*)d_in[2];   // [5,32768,3]
    const float* cw  = (const float*)d_in[3];   // [128,128,3,3,3]
    const float* cb  = (const float*)d_in[4];   // [128]
    const float* dw  = (const float*)d_in[5];   // [8,1]
    const float* dbp = (const float*)d_in[6];   // [1]
    float* out = (float*)d_out;                 // [5,32768,1] f32

    float* ws      = (float*)d_ws;
    float* fld     = ws;                          // 737,280 (atomic accumulation target)
    Cell*  cellp   = (Cell*)(ws + 737280);        // 2,949,120 f32-equiv
    float* wR      = ws + 5898240;                // 55,296 (keep prior offsets)
    float* bR      = wR + 55296;                  // 16 (+pad 32)
    float* nearA   = bR + 32;                     // 163,840
    float* farA    = nearA + 163840;              // 163,840
    unsigned* loU  = (unsigned*)(farA + 163840);  // 8
    unsigned* hiU  = loU + 8;                     // 8

    // loU = 0xFFFFFFFF (uint-max, safe for atomicMin on positive-float bits);
    // hiU = 0 (safe for atomicMax); fld zeroed for atomic accumulation.
    hipMemsetAsync(loU, 0xFF, 8 * sizeof(unsigned), stream);
    hipMemsetAsync(hiU, 0x00, 8 * sizeof(unsigned), stream);
    hipMemsetAsync(fld, 0x00, 737280 * sizeof(float), stream);

    hipLaunchKernelGGL(pre_kernel, dim3(856), dim3(256), 0, stream,
                       cw, cb, dw, ro, rd, wR, bR, nearA, farA, loU, hiU);
    hipLaunchKernelGGL(conv_kernel, dim3(48, 5, 12), dim3(96, 2), 0, stream,
                       vol, wR, fld);
    hipLaunchKernelGGL(pack_kernel, dim3(720), dim3(256), 0, stream, fld, bR, cellp);
    hipLaunchKernelGGL(render_kernel, dim3(2560), dim3(256), 0, stream,
                       ro, rd, cellp, nearA, farA, loU, hiU, dbp, out);
}